// Round 13
// baseline (789.571 us; speedup 1.0000x reference)
//
#include <hip/hip_runtime.h>
#include <hip/hip_bf16.h>

#define N_NODES 100000
#define N_EDGES 3200000
#define F_IN    512
#define H_DIM   64
#define C_DIM   64
#define K_STEPS 10
#define ALPHA   0.1f
#define RSTRIDE 96      // max in-degree slots (Poisson λ=32; P(deg>96) ~ 1e-20)
#define NBINS   256
#define BINW    391     // 256*391 = 100096 >= N_NODES
#define SLOTS   16384   // per-bin staging capacity (mean 12500, +35σ)
#define EPB     4096    // edges per binA block

typedef __attribute__((ext_vector_type(8))) short bf16x8;
typedef __attribute__((ext_vector_type(4))) float f32x4;

// ---- bf16 helpers (storage only; all math fp32) ----
__device__ __forceinline__ float bf2f(ushort u) {
    union { unsigned int i; float f; } c; c.i = ((unsigned int)u) << 16; return c.f;
}
__device__ __forceinline__ ushort f2bf(float f) {
    union { float f; unsigned int i; } c; c.f = f;
    unsigned int lsb = (c.i >> 16) & 1u;
    unsigned int r = c.i + 0x7fffu + lsb;   // round to nearest even
    return (ushort)(r >> 16);
}
// packed RNE convert: lo16 = bf16(a), hi16 = bf16(b)  (single VALU op)
__device__ __forceinline__ uint cvtpk(float a, float b) {
    uint r;
    asm("v_cvt_pk_bf16_f32 %0, %1, %2" : "=v"(r) : "v"(a), "v"(b));
    return r;
}

// ---------------------------------------------------------------- pass A: bin edges by dst range
// LDS-sorted per block -> bin-contiguous staging writes. record: src(17b) | dst_local(9b)<<17
// (src,dst) register-cached across passes: edge list read exactly once.
__global__ __launch_bounds__(256) void binA_kernel(
    const int* __restrict__ src, const int* __restrict__ dst,
    int* __restrict__ gcursor, uint* __restrict__ staging, int e)
{
    __shared__ int cnt[NBINS], sbase[NBINS], loff[NBINS], gbase[NBINS];
    __shared__ int wsum[4];
    __shared__ uint recs[EPB];
    __shared__ uchar binarr[EPB];
    int t = threadIdx.x;
    cnt[t] = 0; loff[t] = 0;
    __syncthreads();

    int blk = blockIdx.x * EPB;
    int nhere = e - blk; nhere = (nhere < EPB) ? nhere : EPB;

    int ssr[16], ddr[16];
    // pass 1: load once + histogram
    #pragma unroll
    for (int j = 0; j < EPB / 256; ++j) {
        int i = blk + j * 256 + t;
        bool v = i < e;
        ssr[j] = v ? __builtin_nontemporal_load(&src[i]) : -1;
        ddr[j] = v ? __builtin_nontemporal_load(&dst[i]) : 0;
        if (v) atomicAdd(&cnt[ddr[j] / BINW], 1);
    }
    __syncthreads();

    // exclusive scan over 256 bins (4 waves)
    int lane = t & 63, w = t >> 6;
    int v = cnt[t], incl = v;
    #pragma unroll
    for (int off = 1; off < 64; off <<= 1) {
        int u = __shfl_up(incl, off);
        if (lane >= off) incl += u;
    }
    if (lane == 63) wsum[w] = incl;
    __syncthreads();
    int woff = 0;
    #pragma unroll
    for (int j = 0; j < 4; ++j) woff += (j < w) ? wsum[j] : 0;
    sbase[t] = woff + (incl - v);
    gbase[t] = (v > 0) ? atomicAdd(&gcursor[t], v) : 0;
    __syncthreads();

    // pass 2: place into LDS (bin-sorted) from registers
    #pragma unroll
    for (int j = 0; j < EPB / 256; ++j) {
        if (ssr[j] >= 0) {
            int b = ddr[j] / BINW;
            int dl = ddr[j] - b * BINW;
            int idx = sbase[b] + atomicAdd(&loff[b], 1);
            recs[idx] = (uint)ssr[j] | ((uint)dl << 17);
            binarr[idx] = (uchar)b;
        }
    }
    __syncthreads();

    // pass 3: coalesced copy-out (bin-contiguous runs)
    #pragma unroll
    for (int j = 0; j < EPB / 256; ++j) {
        int idx = j * 256 + t;
        if (idx < nhere) {
            int b = binarr[idx];
            int gp = gbase[b] + (idx - sbase[b]);
            if (gp < SLOTS)
                staging[(size_t)b * SLOTS + gp] = recs[idx];
        }
    }
}

// ---------------------------------------------------------------- pass B: per-bin CSR fill (LDS counters) + dinv/selfc
__global__ __launch_bounds__(512) void binB_kernel(
    const int* __restrict__ gcursor, const uint* __restrict__ staging,
    int* __restrict__ deg, float* __restrict__ dinv, float* __restrict__ selfc,
    int* __restrict__ esrc, int n)
{
    __shared__ int dloc[BINW];
    int b = blockIdx.x, t = threadIdx.x;
    for (int i = t; i < BINW; i += 512) dloc[i] = 0;
    __syncthreads();

    int cnt = gcursor[b];
    cnt = (cnt < SLOTS) ? cnt : SLOTS;
    const uint* st = staging + (size_t)b * SLOTS;
    int nb = b * BINW;

    int j = t;
    for (; j + 1536 < cnt; j += 2048) {
        uint p0 = st[j], p1 = st[j + 512], p2 = st[j + 1024], p3 = st[j + 1536];
        int d0 = p0 >> 17, d1 = p1 >> 17, d2 = p2 >> 17, d3 = p3 >> 17;
        int q0 = atomicAdd(&dloc[d0], 1);
        int q1 = atomicAdd(&dloc[d1], 1);
        int q2 = atomicAdd(&dloc[d2], 1);
        int q3 = atomicAdd(&dloc[d3], 1);
        if (q0 < RSTRIDE) esrc[(size_t)(nb + d0) * RSTRIDE + q0] = (int)(p0 & 0x1FFFFu);
        if (q1 < RSTRIDE) esrc[(size_t)(nb + d1) * RSTRIDE + q1] = (int)(p1 & 0x1FFFFu);
        if (q2 < RSTRIDE) esrc[(size_t)(nb + d2) * RSTRIDE + q2] = (int)(p2 & 0x1FFFFu);
        if (q3 < RSTRIDE) esrc[(size_t)(nb + d3) * RSTRIDE + q3] = (int)(p3 & 0x1FFFFu);
    }
    for (; j < cnt; j += 512) {
        uint p = st[j];
        int d = p >> 17;
        int q = atomicAdd(&dloc[d], 1);
        if (q < RSTRIDE) esrc[(size_t)(nb + d) * RSTRIDE + q] = (int)(p & 0x1FFFFu);
    }
    __syncthreads();
    for (int i = t; i < BINW; i += 512) {
        int node = nb + i;
        if (node < n) {
            int dg = dloc[i];
            deg[node] = dg;
            float d = rsqrtf((float)dg + 1.0f);
            dinv[node]  = d;
            selfc[node] = (1.0f - ALPHA) * d * d;
        }
    }
}

// ---------------------------------------------------------------- convert weights to bf16
__global__ void cvt_w_kernel(const float* __restrict__ W1, const float* __restrict__ W2,
                             ushort* __restrict__ w1bf, ushort* __restrict__ w2bf) {
    int i = blockIdx.x * blockDim.x + threadIdx.x;
    if (i < 64 * 512) w1bf[i] = f2bf(W1[i]);
    if (i < 64 * 64)  w2bf[i] = f2bf(W2[i]);
}

// ---------------------------------------------------------------- fused MFMA MLP -> y0 = dinv*h
// 64-thread blocks (1 wave, 32 rows each), grid ~3125 -> ~12 waves/CU supply.
// W1, W2 read direct from global (L1/L2-served); only h1 transpose staging in LDS.
__global__ __launch_bounds__(64, 8) void mlp_mfma_kernel(
    const float* __restrict__ x, const ushort* __restrict__ w1bf, const float* __restrict__ b1,
    const ushort* __restrict__ w2bf, const float* __restrict__ b2, const float* __restrict__ dinv,
    ushort* __restrict__ y0, int n)
{
    __shared__ ushort h1s[2048];       // 32x64 bf16, swizzled
    __shared__ float  b1s[64], b2s[64];

    int t = threadIdx.x;               // 0..63
    b1s[t] = b1[t];
    b2s[t] = b2[t];
    __syncthreads();

    int lr = t & 15;
    int lk = t >> 4;
    int rowbase = blockIdx.x * 32;

    f32x4 acc[2][4] = {};
    for (int kk = 0; kk < 16; ++kk) {
        int k0 = kk * 32 + lk * 8;
        bf16x8 a[2];
        #pragma unroll
        for (int fr = 0; fr < 2; ++fr) {
            int row = rowbase + fr * 16 + lr;
            row = (row < n) ? row : (n - 1);
            const float* p = x + (size_t)row * F_IN + k0;
            f32x4 u0 = __builtin_nontemporal_load(reinterpret_cast<const f32x4*>(p));
            f32x4 u1 = __builtin_nontemporal_load(reinterpret_cast<const f32x4*>(p + 4));
            union { uint u[4]; bf16x8 v; } pk;
            pk.u[0] = cvtpk(u0[0], u0[1]);
            pk.u[1] = cvtpk(u0[2], u0[3]);
            pk.u[2] = cvtpk(u1[0], u1[1]);
            pk.u[3] = cvtpk(u1[2], u1[3]);
            a[fr] = pk.v;
        }
        bf16x8 b[4];
        #pragma unroll
        for (int fc = 0; fc < 4; ++fc) {
            int nn = fc * 16 + lr;
            b[fc] = *reinterpret_cast<const bf16x8*>(w1bf + (size_t)nn * F_IN + k0);
        }
        #pragma unroll
        for (int fr = 0; fr < 2; ++fr)
            #pragma unroll
            for (int fc = 0; fc < 4; ++fc)
                acc[fr][fc] = __builtin_amdgcn_mfma_f32_16x16x32_bf16(a[fr], b[fc], acc[fr][fc], 0, 0, 0);
    }

    // bias + relu -> LDS transpose staging (swizzled)
    #pragma unroll
    for (int fr = 0; fr < 2; ++fr) {
        #pragma unroll
        for (int fc = 0; fc < 4; ++fc) {
            #pragma unroll
            for (int reg = 0; reg < 4; ++reg) {
                float vv = acc[fr][fc][reg] + b1s[fc * 16 + lr];
                vv = fmaxf(vv, 0.f);
                int row = fr * 16 + lk * 4 + reg;
                int col = fc * 16 + lr;
                int byte = row * 128 + col * 2;
                *reinterpret_cast<ushort*>((char*)h1s + (byte ^ ((row & 7) << 4))) = f2bf(vv);
            }
        }
    }
    __syncthreads();

    f32x4 acc2[2][4] = {};
    #pragma unroll
    for (int kk = 0; kk < 2; ++kk) {
        int k0 = kk * 32 + lk * 8;
        bf16x8 a2[2], bb[4];
        #pragma unroll
        for (int fr = 0; fr < 2; ++fr) {
            int row = fr * 16 + lr;
            int byte = row * 128 + k0 * 2;
            a2[fr] = *reinterpret_cast<const bf16x8*>((char*)h1s + (byte ^ ((row & 7) << 4)));
        }
        #pragma unroll
        for (int fc = 0; fc < 4; ++fc) {
            int nn = fc * 16 + lr;
            bb[fc] = *reinterpret_cast<const bf16x8*>(w2bf + (size_t)nn * H_DIM + k0);
        }
        #pragma unroll
        for (int fr = 0; fr < 2; ++fr)
            #pragma unroll
            for (int fc = 0; fc < 4; ++fc)
                acc2[fr][fc] = __builtin_amdgcn_mfma_f32_16x16x32_bf16(a2[fr], bb[fc], acc2[fr][fc], 0, 0, 0);
    }

    #pragma unroll
    for (int fr = 0; fr < 2; ++fr) {
        #pragma unroll
        for (int fc = 0; fc < 4; ++fc) {
            #pragma unroll
            for (int reg = 0; reg < 4; ++reg) {
                int row = rowbase + fr * 16 + lk * 4 + reg;
                int col = fc * 16 + lr;
                if (row < n) {
                    float hv = (acc2[fr][fc][reg] + b2s[col]) * dinv[row];
                    y0[(size_t)row * 64 + col] = f2bf(hv);
                }
            }
        }
    }
}

// ---------------------------------------------------------------- APPNP step
// wave = 1 node; 8 edges x 8 lanes x uint4 (8 bf16 channels per lane) -> one
// gather instruction moves 8 full 128B rows (1KB). 32-edge main unroll
// (4 gathers in flight) + 16-edge mid + 8-edge tail.
// y' = selfc*(sum_src y[src] + y) + alpha*y0 ; LAST fuses log_softmax of z = y'/dinv.
template<bool LAST>
__global__ __launch_bounds__(256) void appnp_step_kernel(
    const int* __restrict__ deg, const int* __restrict__ esrc,
    const float* __restrict__ selfc, const float* __restrict__ dinv,
    const ushort* __restrict__ yin, const ushort* __restrict__ y0buf,
    ushort* __restrict__ yout, float* __restrict__ lsm, int n)
{
    int idx = blockIdx.x * blockDim.x + threadIdx.x;
    int wid = idx >> 6;
    if (wid >= n) return;
    int lane = threadIdx.x & 63;
    int q = lane >> 3;     // which of 8 concurrent edges
    int p = lane & 7;      // uint4 slot within row -> channels 8p..8p+7
    const uint4* y4 = (const uint4*)yin;
    int cnt = deg[wid];
    cnt = (cnt < RSTRIDE) ? cnt : RSTRIDE;
    int base = wid * RSTRIDE;

    float a0 = 0.f, a1 = 0.f, a2 = 0.f, a3 = 0.f;
    float a4 = 0.f, a5 = 0.f, a6 = 0.f, a7 = 0.f;
    int e = 0;
    for (; e + 31 < cnt; e += 32) {
        int s0 = __builtin_nontemporal_load(&esrc[base + e + q]);
        int s1 = __builtin_nontemporal_load(&esrc[base + e + 8 + q]);
        int s2 = __builtin_nontemporal_load(&esrc[base + e + 16 + q]);
        int s3 = __builtin_nontemporal_load(&esrc[base + e + 24 + q]);
        uint4 v0 = y4[(size_t)s0 * 8 + p];
        uint4 v1 = y4[(size_t)s1 * 8 + p];
        uint4 v2 = y4[(size_t)s2 * 8 + p];
        uint4 v3 = y4[(size_t)s3 * 8 + p];
        a0 += bf2f((ushort)v0.x) + bf2f((ushort)v1.x) + bf2f((ushort)v2.x) + bf2f((ushort)v3.x);
        a1 += bf2f((ushort)(v0.x >> 16)) + bf2f((ushort)(v1.x >> 16)) +
              bf2f((ushort)(v2.x >> 16)) + bf2f((ushort)(v3.x >> 16));
        a2 += bf2f((ushort)v0.y) + bf2f((ushort)v1.y) + bf2f((ushort)v2.y) + bf2f((ushort)v3.y);
        a3 += bf2f((ushort)(v0.y >> 16)) + bf2f((ushort)(v1.y >> 16)) +
              bf2f((ushort)(v2.y >> 16)) + bf2f((ushort)(v3.y >> 16));
        a4 += bf2f((ushort)v0.z) + bf2f((ushort)v1.z) + bf2f((ushort)v2.z) + bf2f((ushort)v3.z);
        a5 += bf2f((ushort)(v0.z >> 16)) + bf2f((ushort)(v1.z >> 16)) +
              bf2f((ushort)(v2.z >> 16)) + bf2f((ushort)(v3.z >> 16));
        a6 += bf2f((ushort)v0.w) + bf2f((ushort)v1.w) + bf2f((ushort)v2.w) + bf2f((ushort)v3.w);
        a7 += bf2f((ushort)(v0.w >> 16)) + bf2f((ushort)(v1.w >> 16)) +
              bf2f((ushort)(v2.w >> 16)) + bf2f((ushort)(v3.w >> 16));
    }
    if (e + 15 < cnt) {
        int s0 = __builtin_nontemporal_load(&esrc[base + e + q]);
        int s1 = __builtin_nontemporal_load(&esrc[base + e + 8 + q]);
        uint4 v0 = y4[(size_t)s0 * 8 + p];
        uint4 v1 = y4[(size_t)s1 * 8 + p];
        a0 += bf2f((ushort)v0.x) + bf2f((ushort)v1.x);
        a1 += bf2f((ushort)(v0.x >> 16)) + bf2f((ushort)(v1.x >> 16));
        a2 += bf2f((ushort)v0.y) + bf2f((ushort)v1.y);
        a3 += bf2f((ushort)(v0.y >> 16)) + bf2f((ushort)(v1.y >> 16));
        a4 += bf2f((ushort)v0.z) + bf2f((ushort)v1.z);
        a5 += bf2f((ushort)(v0.z >> 16)) + bf2f((ushort)(v1.z >> 16));
        a6 += bf2f((ushort)v0.w) + bf2f((ushort)v1.w);
        a7 += bf2f((ushort)(v0.w >> 16)) + bf2f((ushort)(v1.w >> 16));
        e += 16;
    }
    for (; e < cnt; e += 8) {
        bool valid = (e + q) < cnt;
        int s = __builtin_nontemporal_load(&esrc[valid ? (base + e + q) : base]);
        uint4 v = y4[(size_t)s * 8 + p];
        if (valid) {
            a0 += bf2f((ushort)v.x); a1 += bf2f((ushort)(v.x >> 16));
            a2 += bf2f((ushort)v.y); a3 += bf2f((ushort)(v.y >> 16));
            a4 += bf2f((ushort)v.z); a5 += bf2f((ushort)(v.z >> 16));
            a6 += bf2f((ushort)v.w); a7 += bf2f((ushort)(v.w >> 16));
        }
    }
    // reduce across the 8 q-groups: after xor 8,16,32 every lane holds full sums
    a0 += __shfl_xor(a0, 8); a0 += __shfl_xor(a0, 16); a0 += __shfl_xor(a0, 32);
    a1 += __shfl_xor(a1, 8); a1 += __shfl_xor(a1, 16); a1 += __shfl_xor(a1, 32);
    a2 += __shfl_xor(a2, 8); a2 += __shfl_xor(a2, 16); a2 += __shfl_xor(a2, 32);
    a3 += __shfl_xor(a3, 8); a3 += __shfl_xor(a3, 16); a3 += __shfl_xor(a3, 32);
    a4 += __shfl_xor(a4, 8); a4 += __shfl_xor(a4, 16); a4 += __shfl_xor(a4, 32);
    a5 += __shfl_xor(a5, 8); a5 += __shfl_xor(a5, 16); a5 += __shfl_xor(a5, 32);
    a6 += __shfl_xor(a6, 8); a6 += __shfl_xor(a6, 16); a6 += __shfl_xor(a6, 32);
    a7 += __shfl_xor(a7, 8); a7 += __shfl_xor(a7, 16); a7 += __shfl_xor(a7, 32);

    size_t o4 = (size_t)wid * 8 + p;
    uint4 ys = y4[o4];
    uint4 gg = ((const uint4*)y0buf)[o4];
    float sc = selfc[wid];
    float yn0 = sc * (a0 + bf2f((ushort)ys.x)) + ALPHA * bf2f((ushort)gg.x);
    float yn1 = sc * (a1 + bf2f((ushort)(ys.x >> 16))) + ALPHA * bf2f((ushort)(gg.x >> 16));
    float yn2 = sc * (a2 + bf2f((ushort)ys.y)) + ALPHA * bf2f((ushort)gg.y);
    float yn3 = sc * (a3 + bf2f((ushort)(ys.y >> 16))) + ALPHA * bf2f((ushort)(gg.y >> 16));
    float yn4 = sc * (a4 + bf2f((ushort)ys.z)) + ALPHA * bf2f((ushort)gg.z);
    float yn5 = sc * (a5 + bf2f((ushort)(ys.z >> 16))) + ALPHA * bf2f((ushort)(gg.z >> 16));
    float yn6 = sc * (a6 + bf2f((ushort)ys.w)) + ALPHA * bf2f((ushort)gg.w);
    float yn7 = sc * (a7 + bf2f((ushort)(ys.w >> 16))) + ALPHA * bf2f((ushort)(gg.w >> 16));

    if (!LAST) {
        if (q == 0) {
            uint4 pk;
            pk.x = cvtpk(yn0, yn1);
            pk.y = cvtpk(yn2, yn3);
            pk.z = cvtpk(yn4, yn5);
            pk.w = cvtpk(yn6, yn7);
            ((uint4*)yout)[o4] = pk;
        }
    } else {
        float di = dinv[wid];
        float z0 = yn0 / di, z1 = yn1 / di, z2 = yn2 / di, z3 = yn3 / di;
        float z4 = yn4 / di, z5 = yn5 / di, z6 = yn6 / di, z7 = yn7 / di;
        float m = fmaxf(fmaxf(fmaxf(z0, z1), fmaxf(z2, z3)),
                        fmaxf(fmaxf(z4, z5), fmaxf(z6, z7)));
        #pragma unroll
        for (int off = 4; off > 0; off >>= 1) m = fmaxf(m, __shfl_xor(m, off));
        float s = expf(z0 - m) + expf(z1 - m) + expf(z2 - m) + expf(z3 - m) +
                  expf(z4 - m) + expf(z5 - m) + expf(z6 - m) + expf(z7 - m);
        #pragma unroll
        for (int off = 4; off > 0; off >>= 1) s += __shfl_xor(s, off);
        float ls = logf(s);
        if (q == 0) {
            float* o = &lsm[(size_t)wid * 64 + 8 * p];
            *reinterpret_cast<float4*>(o)     = make_float4(z0 - m - ls, z1 - m - ls,
                                                            z2 - m - ls, z3 - m - ls);
            *reinterpret_cast<float4*>(o + 4) = make_float4(z4 - m - ls, z5 - m - ls,
                                                            z6 - m - ls, z7 - m - ls);
        }
    }
}

// ---------------------------------------------------------------- launch
extern "C" void kernel_launch(void* const* d_in, const int* in_sizes, int n_in,
                              void* d_out, int out_size, void* d_ws, size_t ws_size,
                              hipStream_t stream) {
    const float* x  = (const float*)d_in[0];
    const float* W1 = (const float*)d_in[1];
    const float* b1 = (const float*)d_in[2];
    const float* W2 = (const float*)d_in[3];
    const float* b2 = (const float*)d_in[4];
    const int*   ei = (const int*)d_in[5];
    const int* src = ei;
    const int* dst = ei + N_EDGES;
    float* out = (float*)d_out;

    char* ws = (char*)d_ws;
    size_t off = 0;
    auto alloc = [&](size_t bytes) -> void* {
        void* p = ws + off;
        off += (bytes + 255) & ~(size_t)255;
        return p;
    };
    int*    deg     = (int*)   alloc((size_t)N_NODES * 4);
    float*  dinv    = (float*) alloc((size_t)N_NODES * 4);
    float*  selfc   = (float*) alloc((size_t)N_NODES * 4);
    int*    gcursor = (int*)   alloc((size_t)NBINS * 4);
    uint*   staging = (uint*)  alloc((size_t)NBINS * SLOTS * 4);      // 16 MB
    int*    esrc    = (int*)   alloc((size_t)N_NODES * RSTRIDE * 4);  // 38.4 MB
    ushort* y0      = (ushort*)alloc((size_t)N_NODES * 64 * 2);       // immutable after mlp
    ushort* yb      = (ushort*)alloc((size_t)N_NODES * 64 * 2);
    ushort* yc      = (ushort*)alloc((size_t)N_NODES * 64 * 2);
    ushort* w1bf    = (ushort*)alloc((size_t)H_DIM * F_IN * 2);
    ushort* w2bf    = (ushort*)alloc((size_t)C_DIM * H_DIM * 2);

    hipMemsetAsync(gcursor, 0, (size_t)NBINS * 4, stream);
    binA_kernel<<<(N_EDGES + EPB - 1) / EPB, 256, 0, stream>>>(src, dst, gcursor, staging, N_EDGES);
    binB_kernel<<<NBINS, 512, 0, stream>>>(gcursor, staging, deg, dinv, selfc, esrc, N_NODES);
    cvt_w_kernel<<<(H_DIM * F_IN + 255) / 256, 256, 0, stream>>>(W1, W2, w1bf, w2bf);
    mlp_mfma_kernel<<<(N_NODES + 31) / 32, 64, 0, stream>>>(x, w1bf, b1, w2bf, b2, dinv,
                                                            y0, N_NODES);

    const int grid = (N_NODES * 64 + 255) / 256;
    const ushort* yin = y0;
    ushort* yout = yb;
    for (int k = 0; k < K_STEPS - 1; ++k) {
        appnp_step_kernel<false><<<grid, 256, 0, stream>>>(
            deg, esrc, selfc, dinv, yin, y0, yout, nullptr, N_NODES);
        yin = yout;
        yout = (yout == yb) ? yc : yb;
    }
    appnp_step_kernel<true><<<grid, 256, 0, stream>>>(
        deg, esrc, selfc, dinv, yin, y0, nullptr, out, N_NODES);
}

// Round 14
// 750.812 us; speedup vs baseline: 1.0516x; 1.0516x over previous
//
#include <hip/hip_runtime.h>
#include <hip/hip_bf16.h>

#define N_NODES 100000
#define N_EDGES 3200000
#define F_IN    512
#define H_DIM   64
#define C_DIM   64
#define K_STEPS 10
#define ALPHA   0.1f
#define RSTRIDE 96      // max in-degree slots (Poisson λ=32; P(deg>96) ~ 1e-20)
#define NBINS   256
#define BINW    391     // 256*391 = 100096 >= N_NODES
#define SLOTS   16384   // per-bin staging capacity (mean 12500, +35σ)
#define EPB     4096    // edges per binA block

typedef __attribute__((ext_vector_type(8))) short bf16x8;
typedef __attribute__((ext_vector_type(4))) float f32x4;

// ---- bf16 helpers (storage only; all math fp32) ----
__device__ __forceinline__ float bf2f(ushort u) {
    union { unsigned int i; float f; } c; c.i = ((unsigned int)u) << 16; return c.f;
}
__device__ __forceinline__ ushort f2bf(float f) {
    union { float f; unsigned int i; } c; c.f = f;
    unsigned int lsb = (c.i >> 16) & 1u;
    unsigned int r = c.i + 0x7fffu + lsb;   // round to nearest even
    return (ushort)(r >> 16);
}
// packed RNE convert: lo16 = bf16(a), hi16 = bf16(b)  (single VALU op)
__device__ __forceinline__ uint cvtpk(float a, float b) {
    uint r;
    asm("v_cvt_pk_bf16_f32 %0, %1, %2" : "=v"(r) : "v"(a), "v"(b));
    return r;
}

// ---------------------------------------------------------------- pass A: bin edges by dst range
// LDS-sorted per block -> bin-contiguous staging writes. record: src(17b) | dst_local(9b)<<17
// (src,dst) register-cached across passes: edge list read exactly once.
__global__ __launch_bounds__(256) void binA_kernel(
    const int* __restrict__ src, const int* __restrict__ dst,
    int* __restrict__ gcursor, uint* __restrict__ staging, int e)
{
    __shared__ int cnt[NBINS], sbase[NBINS], loff[NBINS], gbase[NBINS];
    __shared__ int wsum[4];
    __shared__ uint recs[EPB];
    __shared__ uchar binarr[EPB];
    int t = threadIdx.x;
    cnt[t] = 0; loff[t] = 0;
    __syncthreads();

    int blk = blockIdx.x * EPB;
    int nhere = e - blk; nhere = (nhere < EPB) ? nhere : EPB;

    int ssr[16], ddr[16];
    // pass 1: load once + histogram
    #pragma unroll
    for (int j = 0; j < EPB / 256; ++j) {
        int i = blk + j * 256 + t;
        bool v = i < e;
        ssr[j] = v ? __builtin_nontemporal_load(&src[i]) : -1;
        ddr[j] = v ? __builtin_nontemporal_load(&dst[i]) : 0;
        if (v) atomicAdd(&cnt[ddr[j] / BINW], 1);
    }
    __syncthreads();

    // exclusive scan over 256 bins (4 waves)
    int lane = t & 63, w = t >> 6;
    int v = cnt[t], incl = v;
    #pragma unroll
    for (int off = 1; off < 64; off <<= 1) {
        int u = __shfl_up(incl, off);
        if (lane >= off) incl += u;
    }
    if (lane == 63) wsum[w] = incl;
    __syncthreads();
    int woff = 0;
    #pragma unroll
    for (int j = 0; j < 4; ++j) woff += (j < w) ? wsum[j] : 0;
    sbase[t] = woff + (incl - v);
    gbase[t] = (v > 0) ? atomicAdd(&gcursor[t], v) : 0;
    __syncthreads();

    // pass 2: place into LDS (bin-sorted) from registers
    #pragma unroll
    for (int j = 0; j < EPB / 256; ++j) {
        if (ssr[j] >= 0) {
            int b = ddr[j] / BINW;
            int dl = ddr[j] - b * BINW;
            int idx = sbase[b] + atomicAdd(&loff[b], 1);
            recs[idx] = (uint)ssr[j] | ((uint)dl << 17);
            binarr[idx] = (uchar)b;
        }
    }
    __syncthreads();

    // pass 3: coalesced copy-out (bin-contiguous runs)
    #pragma unroll
    for (int j = 0; j < EPB / 256; ++j) {
        int idx = j * 256 + t;
        if (idx < nhere) {
            int b = binarr[idx];
            int gp = gbase[b] + (idx - sbase[b]);
            if (gp < SLOTS)
                staging[(size_t)b * SLOTS + gp] = recs[idx];
        }
    }
}

// ---------------------------------------------------------------- pass B: per-bin CSR fill (LDS counters) + dinv/selfc
__global__ __launch_bounds__(512) void binB_kernel(
    const int* __restrict__ gcursor, const uint* __restrict__ staging,
    int* __restrict__ deg, float* __restrict__ dinv, float* __restrict__ selfc,
    int* __restrict__ esrc, int n)
{
    __shared__ int dloc[BINW];
    int b = blockIdx.x, t = threadIdx.x;
    for (int i = t; i < BINW; i += 512) dloc[i] = 0;
    __syncthreads();

    int cnt = gcursor[b];
    cnt = (cnt < SLOTS) ? cnt : SLOTS;
    const uint* st = staging + (size_t)b * SLOTS;
    int nb = b * BINW;

    int j = t;
    for (; j + 1536 < cnt; j += 2048) {
        uint p0 = st[j], p1 = st[j + 512], p2 = st[j + 1024], p3 = st[j + 1536];
        int d0 = p0 >> 17, d1 = p1 >> 17, d2 = p2 >> 17, d3 = p3 >> 17;
        int q0 = atomicAdd(&dloc[d0], 1);
        int q1 = atomicAdd(&dloc[d1], 1);
        int q2 = atomicAdd(&dloc[d2], 1);
        int q3 = atomicAdd(&dloc[d3], 1);
        if (q0 < RSTRIDE) esrc[(size_t)(nb + d0) * RSTRIDE + q0] = (int)(p0 & 0x1FFFFu);
        if (q1 < RSTRIDE) esrc[(size_t)(nb + d1) * RSTRIDE + q1] = (int)(p1 & 0x1FFFFu);
        if (q2 < RSTRIDE) esrc[(size_t)(nb + d2) * RSTRIDE + q2] = (int)(p2 & 0x1FFFFu);
        if (q3 < RSTRIDE) esrc[(size_t)(nb + d3) * RSTRIDE + q3] = (int)(p3 & 0x1FFFFu);
    }
    for (; j < cnt; j += 512) {
        uint p = st[j];
        int d = p >> 17;
        int q = atomicAdd(&dloc[d], 1);
        if (q < RSTRIDE) esrc[(size_t)(nb + d) * RSTRIDE + q] = (int)(p & 0x1FFFFu);
    }
    __syncthreads();
    for (int i = t; i < BINW; i += 512) {
        int node = nb + i;
        if (node < n) {
            int dg = dloc[i];
            deg[node] = dg;
            float d = rsqrtf((float)dg + 1.0f);
            dinv[node]  = d;
            selfc[node] = (1.0f - ALPHA) * d * d;
        }
    }
}

// ---------------------------------------------------------------- convert weights to bf16
__global__ void cvt_w_kernel(const float* __restrict__ W1, const float* __restrict__ W2,
                             ushort* __restrict__ w1bf, ushort* __restrict__ w2bf) {
    int i = blockIdx.x * blockDim.x + threadIdx.x;
    if (i < 64 * 512) w1bf[i] = f2bf(W1[i]);
    if (i < 64 * 64)  w2bf[i] = f2bf(W2[i]);
}

// ---------------------------------------------------------------- fused MFMA MLP -> y0 = dinv*h
// 64-thread blocks (1 wave, 64 rows each), grid ~1563. W1/W2 read direct from
// global (L2-served, 64-row reuse per wave); only h1 transpose staging in LDS.
__global__ __launch_bounds__(64, 4) void mlp_mfma_kernel(
    const float* __restrict__ x, const ushort* __restrict__ w1bf, const float* __restrict__ b1,
    const ushort* __restrict__ w2bf, const float* __restrict__ b2, const float* __restrict__ dinv,
    ushort* __restrict__ y0, int n)
{
    __shared__ ushort h1s[4096];       // 64x64 bf16, swizzled
    __shared__ float  b1s[64], b2s[64];

    int t = threadIdx.x;               // 0..63
    b1s[t] = b1[t];
    b2s[t] = b2[t];
    __syncthreads();

    int lr = t & 15;
    int lk = t >> 4;
    int rowbase = blockIdx.x * 64;

    f32x4 acc[4][4] = {};
    for (int kk = 0; kk < 16; ++kk) {
        int k0 = kk * 32 + lk * 8;
        bf16x8 a[4];
        #pragma unroll
        for (int fr = 0; fr < 4; ++fr) {
            int row = rowbase + fr * 16 + lr;
            row = (row < n) ? row : (n - 1);
            const float* p = x + (size_t)row * F_IN + k0;
            f32x4 u0 = __builtin_nontemporal_load(reinterpret_cast<const f32x4*>(p));
            f32x4 u1 = __builtin_nontemporal_load(reinterpret_cast<const f32x4*>(p + 4));
            union { uint u[4]; bf16x8 v; } pk;
            pk.u[0] = cvtpk(u0[0], u0[1]);
            pk.u[1] = cvtpk(u0[2], u0[3]);
            pk.u[2] = cvtpk(u1[0], u1[1]);
            pk.u[3] = cvtpk(u1[2], u1[3]);
            a[fr] = pk.v;
        }
        bf16x8 b[4];
        #pragma unroll
        for (int fc = 0; fc < 4; ++fc) {
            int nn = fc * 16 + lr;
            b[fc] = *reinterpret_cast<const bf16x8*>(w1bf + (size_t)nn * F_IN + k0);
        }
        #pragma unroll
        for (int fr = 0; fr < 4; ++fr)
            #pragma unroll
            for (int fc = 0; fc < 4; ++fc)
                acc[fr][fc] = __builtin_amdgcn_mfma_f32_16x16x32_bf16(a[fr], b[fc], acc[fr][fc], 0, 0, 0);
    }

    // bias + relu -> LDS transpose staging (swizzled)
    #pragma unroll
    for (int fr = 0; fr < 4; ++fr) {
        #pragma unroll
        for (int fc = 0; fc < 4; ++fc) {
            #pragma unroll
            for (int reg = 0; reg < 4; ++reg) {
                float vv = acc[fr][fc][reg] + b1s[fc * 16 + lr];
                vv = fmaxf(vv, 0.f);
                int row = fr * 16 + lk * 4 + reg;
                int col = fc * 16 + lr;
                int byte = row * 128 + col * 2;
                *reinterpret_cast<ushort*>((char*)h1s + (byte ^ ((row & 7) << 4))) = f2bf(vv);
            }
        }
    }
    __syncthreads();

    f32x4 acc2[4][4] = {};
    #pragma unroll
    for (int kk = 0; kk < 2; ++kk) {
        int k0 = kk * 32 + lk * 8;
        bf16x8 a2[4], bb[4];
        #pragma unroll
        for (int fr = 0; fr < 4; ++fr) {
            int row = fr * 16 + lr;
            int byte = row * 128 + k0 * 2;
            a2[fr] = *reinterpret_cast<const bf16x8*>((char*)h1s + (byte ^ ((row & 7) << 4)));
        }
        #pragma unroll
        for (int fc = 0; fc < 4; ++fc) {
            int nn = fc * 16 + lr;
            bb[fc] = *reinterpret_cast<const bf16x8*>(w2bf + (size_t)nn * H_DIM + k0);
        }
        #pragma unroll
        for (int fr = 0; fr < 4; ++fr)
            #pragma unroll
            for (int fc = 0; fc < 4; ++fc)
                acc2[fr][fc] = __builtin_amdgcn_mfma_f32_16x16x32_bf16(a2[fr], bb[fc], acc2[fr][fc], 0, 0, 0);
    }

    #pragma unroll
    for (int fr = 0; fr < 4; ++fr) {
        #pragma unroll
        for (int fc = 0; fc < 4; ++fc) {
            #pragma unroll
            for (int reg = 0; reg < 4; ++reg) {
                int row = rowbase + fr * 16 + lk * 4 + reg;
                int col = fc * 16 + lr;
                if (row < n) {
                    float hv = (acc2[fr][fc][reg] + b2s[col]) * dinv[row];
                    y0[(size_t)row * 64 + col] = f2bf(hv);
                }
            }
        }
    }
}

// ---------------------------------------------------------------- APPNP step
// wave = 1 node; 8 edges x 8 lanes x uint4 (8 bf16 channels per lane) -> one
// gather instruction moves 8 full 128B rows (1KB). 32-edge main unroll
// (4 gathers in flight) + 16-edge mid + 8-edge tail.
// y' = selfc*(sum_src y[src] + y) + alpha*y0 ; LAST fuses log_softmax of z = y'/dinv.
template<bool LAST>
__global__ __launch_bounds__(256) void appnp_step_kernel(
    const int* __restrict__ deg, const int* __restrict__ esrc,
    const float* __restrict__ selfc, const float* __restrict__ dinv,
    const ushort* __restrict__ yin, const ushort* __restrict__ y0buf,
    ushort* __restrict__ yout, float* __restrict__ lsm, int n)
{
    int idx = blockIdx.x * blockDim.x + threadIdx.x;
    int wid = idx >> 6;
    if (wid >= n) return;
    int lane = threadIdx.x & 63;
    int q = lane >> 3;     // which of 8 concurrent edges
    int p = lane & 7;      // uint4 slot within row -> channels 8p..8p+7
    const uint4* y4 = (const uint4*)yin;
    int cnt = deg[wid];
    cnt = (cnt < RSTRIDE) ? cnt : RSTRIDE;
    int base = wid * RSTRIDE;

    float a0 = 0.f, a1 = 0.f, a2 = 0.f, a3 = 0.f;
    float a4 = 0.f, a5 = 0.f, a6 = 0.f, a7 = 0.f;
    int e = 0;
    for (; e + 31 < cnt; e += 32) {
        int s0 = __builtin_nontemporal_load(&esrc[base + e + q]);
        int s1 = __builtin_nontemporal_load(&esrc[base + e + 8 + q]);
        int s2 = __builtin_nontemporal_load(&esrc[base + e + 16 + q]);
        int s3 = __builtin_nontemporal_load(&esrc[base + e + 24 + q]);
        uint4 v0 = y4[(size_t)s0 * 8 + p];
        uint4 v1 = y4[(size_t)s1 * 8 + p];
        uint4 v2 = y4[(size_t)s2 * 8 + p];
        uint4 v3 = y4[(size_t)s3 * 8 + p];
        a0 += bf2f((ushort)v0.x) + bf2f((ushort)v1.x) + bf2f((ushort)v2.x) + bf2f((ushort)v3.x);
        a1 += bf2f((ushort)(v0.x >> 16)) + bf2f((ushort)(v1.x >> 16)) +
              bf2f((ushort)(v2.x >> 16)) + bf2f((ushort)(v3.x >> 16));
        a2 += bf2f((ushort)v0.y) + bf2f((ushort)v1.y) + bf2f((ushort)v2.y) + bf2f((ushort)v3.y);
        a3 += bf2f((ushort)(v0.y >> 16)) + bf2f((ushort)(v1.y >> 16)) +
              bf2f((ushort)(v2.y >> 16)) + bf2f((ushort)(v3.y >> 16));
        a4 += bf2f((ushort)v0.z) + bf2f((ushort)v1.z) + bf2f((ushort)v2.z) + bf2f((ushort)v3.z);
        a5 += bf2f((ushort)(v0.z >> 16)) + bf2f((ushort)(v1.z >> 16)) +
              bf2f((ushort)(v2.z >> 16)) + bf2f((ushort)(v3.z >> 16));
        a6 += bf2f((ushort)v0.w) + bf2f((ushort)v1.w) + bf2f((ushort)v2.w) + bf2f((ushort)v3.w);
        a7 += bf2f((ushort)(v0.w >> 16)) + bf2f((ushort)(v1.w >> 16)) +
              bf2f((ushort)(v2.w >> 16)) + bf2f((ushort)(v3.w >> 16));
    }
    if (e + 15 < cnt) {
        int s0 = __builtin_nontemporal_load(&esrc[base + e + q]);
        int s1 = __builtin_nontemporal_load(&esrc[base + e + 8 + q]);
        uint4 v0 = y4[(size_t)s0 * 8 + p];
        uint4 v1 = y4[(size_t)s1 * 8 + p];
        a0 += bf2f((ushort)v0.x) + bf2f((ushort)v1.x);
        a1 += bf2f((ushort)(v0.x >> 16)) + bf2f((ushort)(v1.x >> 16));
        a2 += bf2f((ushort)v0.y) + bf2f((ushort)v1.y);
        a3 += bf2f((ushort)(v0.y >> 16)) + bf2f((ushort)(v1.y >> 16));
        a4 += bf2f((ushort)v0.z) + bf2f((ushort)v1.z);
        a5 += bf2f((ushort)(v0.z >> 16)) + bf2f((ushort)(v1.z >> 16));
        a6 += bf2f((ushort)v0.w) + bf2f((ushort)v1.w);
        a7 += bf2f((ushort)(v0.w >> 16)) + bf2f((ushort)(v1.w >> 16));
        e += 16;
    }
    for (; e < cnt; e += 8) {
        bool valid = (e + q) < cnt;
        int s = __builtin_nontemporal_load(&esrc[valid ? (base + e + q) : base]);
        uint4 v = y4[(size_t)s * 8 + p];
        if (valid) {
            a0 += bf2f((ushort)v.x); a1 += bf2f((ushort)(v.x >> 16));
            a2 += bf2f((ushort)v.y); a3 += bf2f((ushort)(v.y >> 16));
            a4 += bf2f((ushort)v.z); a5 += bf2f((ushort)(v.z >> 16));
            a6 += bf2f((ushort)v.w); a7 += bf2f((ushort)(v.w >> 16));
        }
    }
    // reduce across the 8 q-groups: after xor 8,16,32 every lane holds full sums
    a0 += __shfl_xor(a0, 8); a0 += __shfl_xor(a0, 16); a0 += __shfl_xor(a0, 32);
    a1 += __shfl_xor(a1, 8); a1 += __shfl_xor(a1, 16); a1 += __shfl_xor(a1, 32);
    a2 += __shfl_xor(a2, 8); a2 += __shfl_xor(a2, 16); a2 += __shfl_xor(a2, 32);
    a3 += __shfl_xor(a3, 8); a3 += __shfl_xor(a3, 16); a3 += __shfl_xor(a3, 32);
    a4 += __shfl_xor(a4, 8); a4 += __shfl_xor(a4, 16); a4 += __shfl_xor(a4, 32);
    a5 += __shfl_xor(a5, 8); a5 += __shfl_xor(a5, 16); a5 += __shfl_xor(a5, 32);
    a6 += __shfl_xor(a6, 8); a6 += __shfl_xor(a6, 16); a6 += __shfl_xor(a6, 32);
    a7 += __shfl_xor(a7, 8); a7 += __shfl_xor(a7, 16); a7 += __shfl_xor(a7, 32);

    size_t o4 = (size_t)wid * 8 + p;
    uint4 ys = y4[o4];
    uint4 gg = ((const uint4*)y0buf)[o4];
    float sc = selfc[wid];
    float yn0 = sc * (a0 + bf2f((ushort)ys.x)) + ALPHA * bf2f((ushort)gg.x);
    float yn1 = sc * (a1 + bf2f((ushort)(ys.x >> 16))) + ALPHA * bf2f((ushort)(gg.x >> 16));
    float yn2 = sc * (a2 + bf2f((ushort)ys.y)) + ALPHA * bf2f((ushort)gg.y);
    float yn3 = sc * (a3 + bf2f((ushort)(ys.y >> 16))) + ALPHA * bf2f((ushort)(gg.y >> 16));
    float yn4 = sc * (a4 + bf2f((ushort)ys.z)) + ALPHA * bf2f((ushort)gg.z);
    float yn5 = sc * (a5 + bf2f((ushort)(ys.z >> 16))) + ALPHA * bf2f((ushort)(gg.z >> 16));
    float yn6 = sc * (a6 + bf2f((ushort)ys.w)) + ALPHA * bf2f((ushort)gg.w);
    float yn7 = sc * (a7 + bf2f((ushort)(ys.w >> 16))) + ALPHA * bf2f((ushort)(gg.w >> 16));

    if (!LAST) {
        if (q == 0) {
            uint4 pk;
            pk.x = cvtpk(yn0, yn1);
            pk.y = cvtpk(yn2, yn3);
            pk.z = cvtpk(yn4, yn5);
            pk.w = cvtpk(yn6, yn7);
            ((uint4*)yout)[o4] = pk;
        }
    } else {
        float di = dinv[wid];
        float z0 = yn0 / di, z1 = yn1 / di, z2 = yn2 / di, z3 = yn3 / di;
        float z4 = yn4 / di, z5 = yn5 / di, z6 = yn6 / di, z7 = yn7 / di;
        float m = fmaxf(fmaxf(fmaxf(z0, z1), fmaxf(z2, z3)),
                        fmaxf(fmaxf(z4, z5), fmaxf(z6, z7)));
        #pragma unroll
        for (int off = 4; off > 0; off >>= 1) m = fmaxf(m, __shfl_xor(m, off));
        float s = expf(z0 - m) + expf(z1 - m) + expf(z2 - m) + expf(z3 - m) +
                  expf(z4 - m) + expf(z5 - m) + expf(z6 - m) + expf(z7 - m);
        #pragma unroll
        for (int off = 4; off > 0; off >>= 1) s += __shfl_xor(s, off);
        float ls = logf(s);
        if (q == 0) {
            float* o = &lsm[(size_t)wid * 64 + 8 * p];
            *reinterpret_cast<float4*>(o)     = make_float4(z0 - m - ls, z1 - m - ls,
                                                            z2 - m - ls, z3 - m - ls);
            *reinterpret_cast<float4*>(o + 4) = make_float4(z4 - m - ls, z5 - m - ls,
                                                            z6 - m - ls, z7 - m - ls);
        }
    }
}

// ---------------------------------------------------------------- launch
extern "C" void kernel_launch(void* const* d_in, const int* in_sizes, int n_in,
                              void* d_out, int out_size, void* d_ws, size_t ws_size,
                              hipStream_t stream) {
    const float* x  = (const float*)d_in[0];
    const float* W1 = (const float*)d_in[1];
    const float* b1 = (const float*)d_in[2];
    const float* W2 = (const float*)d_in[3];
    const float* b2 = (const float*)d_in[4];
    const int*   ei = (const int*)d_in[5];
    const int* src = ei;
    const int* dst = ei + N_EDGES;
    float* out = (float*)d_out;

    char* ws = (char*)d_ws;
    size_t off = 0;
    auto alloc = [&](size_t bytes) -> void* {
        void* p = ws + off;
        off += (bytes + 255) & ~(size_t)255;
        return p;
    };
    int*    deg     = (int*)   alloc((size_t)N_NODES * 4);
    float*  dinv    = (float*) alloc((size_t)N_NODES * 4);
    float*  selfc   = (float*) alloc((size_t)N_NODES * 4);
    int*    gcursor = (int*)   alloc((size_t)NBINS * 4);
    uint*   staging = (uint*)  alloc((size_t)NBINS * SLOTS * 4);      // 16 MB
    int*    esrc    = (int*)   alloc((size_t)N_NODES * RSTRIDE * 4);  // 38.4 MB
    ushort* y0      = (ushort*)alloc((size_t)N_NODES * 64 * 2);       // immutable after mlp
    ushort* yb      = (ushort*)alloc((size_t)N_NODES * 64 * 2);
    ushort* yc      = (ushort*)alloc((size_t)N_NODES * 64 * 2);
    ushort* w1bf    = (ushort*)alloc((size_t)H_DIM * F_IN * 2);
    ushort* w2bf    = (ushort*)alloc((size_t)C_DIM * H_DIM * 2);

    hipMemsetAsync(gcursor, 0, (size_t)NBINS * 4, stream);
    binA_kernel<<<(N_EDGES + EPB - 1) / EPB, 256, 0, stream>>>(src, dst, gcursor, staging, N_EDGES);
    binB_kernel<<<NBINS, 512, 0, stream>>>(gcursor, staging, deg, dinv, selfc, esrc, N_NODES);
    cvt_w_kernel<<<(H_DIM * F_IN + 255) / 256, 256, 0, stream>>>(W1, W2, w1bf, w2bf);
    mlp_mfma_kernel<<<(N_NODES + 63) / 64, 64, 0, stream>>>(x, w1bf, b1, w2bf, b2, dinv,
                                                            y0, N_NODES);

    const int grid = (N_NODES * 64 + 255) / 256;
    const ushort* yin = y0;
    ushort* yout = yb;
    for (int k = 0; k < K_STEPS - 1; ++k) {
        appnp_step_kernel<false><<<grid, 256, 0, stream>>>(
            deg, esrc, selfc, dinv, yin, y0, yout, nullptr, N_NODES);
        yin = yout;
        yout = (yout == yb) ? yc : yb;
    }
    appnp_step_kernel<true><<<grid, 256, 0, stream>>>(
        deg, esrc, selfc, dinv, yin, y0, nullptr, out, N_NODES);
}